// Round 22
// baseline (415.688 us; speedup 1.0000x reference)
//
#include <hip/hip_runtime.h>
#include <math.h>

#define NPTS 8192
#define NB 2
#define FDIM 96
#define KNN 20
#define VN_EPS 1e-6f
#define VN_BN_EPS 1e-5f
#define NSAMP 768           // sampled cols for threshold estimate
#define PSLOT 12            // candidate slots per (row, 128-col panel), mean ~3.4
#define NPAN 64             // NPTS / 128
#define ROWSLOT (NPAN * PSLOT)   // 768 slots per row
#define CAPS 12             // ROWSLOT / 64
#define OVCAP 64            // per-row overflow spill slots

typedef float f32x16 __attribute__((ext_vector_type(16)));
typedef _Float16 f16x8 __attribute__((ext_vector_type(8)));
typedef unsigned short u16x8 __attribute__((ext_vector_type(8)));

#define WAVESYNC()                                            \
    do {                                                      \
        asm volatile("s_waitcnt lgkmcnt(0)" ::: "memory");    \
        __builtin_amdgcn_wave_barrier();                      \
        asm volatile("" ::: "memory");                        \
    } while (0)

__device__ __forceinline__ unsigned orderable(float v) {
    unsigned u = __float_as_uint(v);
    return (u & 0x80000000u) ? ~u : (u | 0x80000000u);
}
__device__ __forceinline__ float unorderable(unsigned k) {
    unsigned u = (k & 0x80000000u) ? (k & 0x7fffffffu) : ~k;
    return __uint_as_float(u);
}

// ---------------- Kernel 1: xx = sum_f xf^2  AND  xs = f16 split table ----------------
__global__ __launch_bounds__(256) void k_prep(const float* __restrict__ x,
                                              float* __restrict__ xx,
                                              unsigned short* __restrict__ xs) {
    int m = blockIdx.x * 256 + threadIdx.x;
    int b = m >> 13, n = m & 8191;
    const float* xf = x + (size_t)b * FDIM * NPTS;
    unsigned short* row = xs + (size_t)m * 192;
    float s = 0.f;
    for (int fc = 0; fc < 12; ++fc) {
        u16x8 hv, lv;
        #pragma unroll
        for (int j = 0; j < 8; ++j) {
            float vv = xf[(size_t)(fc * 8 + j) * NPTS + n];
            s += vv * vv;
            _Float16 h = (_Float16)vv;
            float hf = (float)h;
            _Float16 l = (_Float16)(vv - hf);
            union { _Float16 f; unsigned short u; } ch, cl;
            ch.f = h; cl.f = l;
            hv[j] = ch.u; lv[j] = cl.u;
        }
        *(u16x8*)(row + fc * 8) = hv;
        *(u16x8*)(row + 96 + fc * 8) = lv;
    }
    xx[m] = s;
}

// ================= shared GEMM structure (k_thr / k_distf), 128x128 tile =================
// 4 waves x 32 rows x 128 cols. A-hi in regs, A-lo reloaded after pass 2.
// Pass chain per value: hl, hh, lh -> bitwise-identical between k_thr and k_distf.
// launch_bounds stays (256,3): natural reg footprint ~148 (84 arch + 64 acc);
// tighter bound spills accumulators to scratch (R20: 6x regression).

// ---------------- Kernel 2a: sampled neg-dist (cols 0..767) -> minibuf ----------------
__global__ __launch_bounds__(256, 3) void k_thr(const unsigned short* __restrict__ xs,
                                                const float* __restrict__ xx,
                                                float* __restrict__ minibuf) {
    __shared__ __align__(16) unsigned short Bsl[128][104];
    __shared__ float sxr[128];
    __shared__ float sxc[128];
    int t = threadIdx.x;
    int lane = t & 63, wid = t >> 6;
    int l31 = lane & 31, hi = lane >> 5;
    int row0 = blockIdx.x * 128;
    int b = row0 >> 13;
    int panel = blockIdx.y;                  // 0..5
    int m0 = panel * 128;
    const unsigned short* xsb = xs + (size_t)b * NPTS * 192;
    int n0w = (row0 & 8191) + wid * 32;

    f16x8 af[6];
    const unsigned short* arow = xsb + (size_t)(n0w + l31) * 192 + hi * 8;
    #pragma unroll
    for (int ks = 0; ks < 6; ++ks) af[ks] = *(const f16x8*)(arow + ks * 16);   // A-hi

    if (t < 128) {
        sxr[t] = xx[row0 + t];
        sxc[t] = xx[(b << 13) + m0 + t];
    }

    f32x16 acc[4];
    #pragma unroll
    for (int ct = 0; ct < 4; ++ct)
        #pragma unroll
        for (int e = 0; e < 16; ++e) acc[ct][e] = 0.f;

    int sc2 = t >> 1, sh2 = t & 1;
    auto stageB = [&](int part) {
        const unsigned short* sb = xsb + (size_t)(m0 + sc2) * 192 + part * 96 + sh2 * 48;
        unsigned short* db = &Bsl[sc2][sh2 * 48];
        #pragma unroll
        for (int j = 0; j < 6; ++j) *(u16x8*)(db + j * 8) = *(const u16x8*)(sb + j * 8);
    };
    auto mmpass = [&]() {
        #pragma unroll
        for (int ks = 0; ks < 6; ++ks)
            #pragma unroll
            for (int ct = 0; ct < 4; ++ct) {
                f16x8 bf = *(const f16x8*)&Bsl[ct * 32 + l31][ks * 16 + hi * 8];
                acc[ct] = __builtin_amdgcn_mfma_f32_32x32x16_f16(af[ks], bf, acc[ct], 0, 0, 0);
            }
    };

    stageB(1);                   // B lo
    __syncthreads();
    mmpass();                    // hA*lB
    __syncthreads();
    stageB(0);                   // B hi
    __syncthreads();
    mmpass();                    // hA*hB
    #pragma unroll
    for (int ks = 0; ks < 6; ++ks) af[ks] = *(const f16x8*)(arow + 96 + ks * 16);  // A-lo
    mmpass();                    // lA*hB

    float xc[4];
    #pragma unroll
    for (int ct = 0; ct < 4; ++ct) xc[ct] = sxc[ct * 32 + l31];
    #pragma unroll
    for (int q = 0; q < 4; ++q)
        #pragma unroll
        for (int rr = 0; rr < 4; ++rr) {
            int rowin = wid * 32 + 4 * hi + 8 * q + rr;
            float xr = sxr[rowin];
            #pragma unroll
            for (int ct = 0; ct < 4; ++ct) {
                float valx = 2.f * acc[ct][q * 4 + rr] - xr - xc[ct];
                minibuf[(size_t)(row0 + rowin) * NSAMP + m0 + ct * 32 + l31] = valx;
            }
        }
}

// ---------------- Kernel 2b: per-row threshold (float form) from sample ----------------
__global__ __launch_bounds__(256) void k_thrsel(const float* __restrict__ minibuf,
                                                float* __restrict__ tauF) {
    int t = threadIdx.x;
    int lane = t & 63, w = t >> 6;
    int r = blockIdx.x * 4 + w;
    const float* mp = minibuf + (size_t)r * NSAMP;
    unsigned key[12];
    #pragma unroll
    for (int s = 0; s < 12; ++s) key[s] = orderable(mp[lane + s * 64]);
    unsigned lo = 0, hi = 0x10000u;
    for (int it = 0; it < 16; ++it) {
        unsigned mid = (lo + hi) >> 1;
        unsigned mkey = mid << 16;
        int c = 0;
        #pragma unroll
        for (int s = 0; s < 12; ++s) c += (key[s] >= mkey) ? 1 : 0;
        #pragma unroll
        for (int d = 1; d < 64; d <<= 1) c += __shfl_xor(c, d);
        if (c >= KNN) lo = mid; else hi = mid;
    }
    if (lane == 0) tauF[r] = unorderable(lo << 16);
}

// ---------------- Kernel 3: full neg-dist + LDS-counter candidate filter ----------------
// Hot path per value: fma + cmp (+ rare branch). Survivors take pos from an LDS
// per-row atomic counter (slot ORDER is irrelevant: k_mrg ranks by (key,col), a
// strict total order -> output deterministic for any slot permutation).
__global__ __launch_bounds__(256, 3) void k_distf(const unsigned short* __restrict__ xs,
                                                  const float* __restrict__ xx,
                                                  const float* __restrict__ tauF,
                                                  unsigned* __restrict__ cnt2d,
                                                  unsigned long long* __restrict__ cand,
                                                  unsigned* __restrict__ ovcnt,
                                                  unsigned long long* __restrict__ ovbuf) {
    __shared__ __align__(16) unsigned short Bsl[128][104];
    __shared__ float sxr[128];
    __shared__ float sxc[128];
    __shared__ float stau[128];
    __shared__ unsigned scount[128];
    int t = threadIdx.x;
    int lane = t & 63, wid = t >> 6;
    int l31 = lane & 31, hi = lane >> 5;
    int row0 = blockIdx.x * 128;
    int b = row0 >> 13;
    int panel = blockIdx.y;                  // 0..63
    int m0 = panel * 128;
    const unsigned short* xsb = xs + (size_t)b * NPTS * 192;
    int n0w = (row0 & 8191) + wid * 32;

    f16x8 af[6];
    const unsigned short* arow = xsb + (size_t)(n0w + l31) * 192 + hi * 8;
    #pragma unroll
    for (int ks = 0; ks < 6; ++ks) af[ks] = *(const f16x8*)(arow + ks * 16);   // A-hi

    if (t < 128) {
        sxr[t] = xx[row0 + t];
        stau[t] = tauF[row0 + t];
        sxc[t] = xx[(b << 13) + m0 + t];
        scount[t] = 0;
    }

    f32x16 acc[4];
    #pragma unroll
    for (int ct = 0; ct < 4; ++ct)
        #pragma unroll
        for (int e = 0; e < 16; ++e) acc[ct][e] = 0.f;

    int sc2 = t >> 1, sh2 = t & 1;
    auto stageB = [&](int part) {
        const unsigned short* sb = xsb + (size_t)(m0 + sc2) * 192 + part * 96 + sh2 * 48;
        unsigned short* db = &Bsl[sc2][sh2 * 48];
        #pragma unroll
        for (int j = 0; j < 6; ++j) *(u16x8*)(db + j * 8) = *(const u16x8*)(sb + j * 8);
    };
    auto mmpass = [&]() {
        #pragma unroll
        for (int ks = 0; ks < 6; ++ks)
            #pragma unroll
            for (int ct = 0; ct < 4; ++ct) {
                f16x8 bf = *(const f16x8*)&Bsl[ct * 32 + l31][ks * 16 + hi * 8];
                acc[ct] = __builtin_amdgcn_mfma_f32_32x32x16_f16(af[ks], bf, acc[ct], 0, 0, 0);
            }
    };

    stageB(1);                   // B lo   (scount init lands before this barrier)
    __syncthreads();
    mmpass();                    // hA*lB
    __syncthreads();
    stageB(0);                   // B hi
    __syncthreads();
    mmpass();                    // hA*hB
    #pragma unroll
    for (int ks = 0; ks < 6; ++ks) af[ks] = *(const f16x8*)(arow + 96 + ks * 16);  // A-lo
    mmpass();                    // lA*hB

    float xc[4];
    #pragma unroll
    for (int ct = 0; ct < 4; ++ct) xc[ct] = sxc[ct * 32 + l31];
    #pragma unroll
    for (int q = 0; q < 4; ++q)
        #pragma unroll
        for (int rr = 0; rr < 4; ++rr) {
            int rowin = wid * 32 + 4 * hi + 8 * q + rr;
            int grow = row0 + rowin;
            float xr = sxr[rowin];
            float tau = stau[rowin];
            size_t base = (size_t)grow * ROWSLOT + (size_t)panel * PSLOT;
            #pragma unroll
            for (int ct = 0; ct < 4; ++ct) {
                float valx = 2.f * acc[ct][q * 4 + rr] - xr - xc[ct];
                if (valx >= tau) {
                    unsigned key = orderable(valx);
                    unsigned long long e = ((unsigned long long)key << 32)
                                         | (unsigned)(m0 + ct * 32 + l31);
                    unsigned pos = atomicAdd(&scount[rowin], 1u);
                    if (pos < PSLOT) {
                        cand[base + pos] = e;
                    } else {            // rare spill: exactness valve
                        unsigned o = atomicAdd(&ovcnt[grow], 1u);
                        if (o < OVCAP) ovbuf[(size_t)grow * OVCAP + o] = e;
                    }
                }
            }
        }
    __syncthreads();
    if (t < 128) {
        unsigned c = scount[t];
        cnt2d[(size_t)(row0 + t) * NPAN + panel] = (c < PSLOT) ? c : PSLOT;
    }
}

// ---------------- Kernel 4: merge candidates + spills -> exact top-20 ----------------
__global__ __launch_bounds__(256) void k_mrg(const unsigned long long* __restrict__ cand,
                                             const unsigned* __restrict__ cnt2d,
                                             const unsigned* __restrict__ ovcnt,
                                             const unsigned long long* __restrict__ ovbuf,
                                             int* __restrict__ idxOut) {
    int t = threadIdx.x;
    int lane = t & 63, w = t >> 6;
    int r = blockIdx.x * 4 + w;
    __shared__ unsigned scc[4][NPAN];
    scc[w][lane] = cnt2d[(size_t)r * NPAN + lane];      // NPAN == 64 == wave size
    WAVESYNC();
    const unsigned long long* cp = cand + (size_t)r * ROWSLOT;
    unsigned long long pk[CAPS + 1];
    #pragma unroll
    for (int s = 0; s < CAPS; ++s) {
        int slot = lane + 64 * s;
        int panel = slot / PSLOT;
        int within = slot - panel * PSLOT;
        pk[s] = (within < (int)scc[w][panel]) ? cp[slot] : 0ull;   // key 0 << real keys
    }
    int ovn = (int)ovcnt[r]; if (ovn > OVCAP) ovn = OVCAP;
    pk[CAPS] = (lane < ovn) ? ovbuf[(size_t)r * OVCAP + lane] : 0ull;

    unsigned lo = 0, hi = 0x10000u;
    for (int it = 0; it < 16; ++it) {
        unsigned mid = (lo + hi) >> 1;
        unsigned mkey = mid << 16;
        int c = 0;
        #pragma unroll
        for (int s = 0; s <= CAPS; ++s) c += ((unsigned)(pk[s] >> 32) >= mkey) ? 1 : 0;
        #pragma unroll
        for (int d = 1; d < 64; d <<= 1) c += __shfl_xor(c, d);
        if (c >= KNN) lo = mid; else hi = mid;
    }
    unsigned thr = lo << 16;

    __shared__ unsigned long long sk[4][128];
    __shared__ int sn[4];
    if (lane == 0) sn[w] = 0;
    WAVESYNC();
    #pragma unroll
    for (int s = 0; s <= CAPS; ++s) {
        if ((unsigned)(pk[s] >> 32) >= thr) {
            int j = atomicAdd(&sn[w], 1);
            if (j < 128) sk[w][j] = pk[s];
        }
    }
    WAVESYNC();
    int nc = sn[w]; if (nc > 128) nc = 128;
    #pragma unroll
    for (int half = 0; half < 2; ++half) {
        int i = lane + half * 64;
        if (i < nc) {
            unsigned long long me = sk[w][i];
            unsigned km = (unsigned)(me >> 32), cm = (unsigned)me;
            int rank = 0;
            for (int j = 0; j < nc; ++j) {
                unsigned long long o = sk[w][j];
                unsigned ko = (unsigned)(o >> 32), co = (unsigned)o;
                rank += (ko > km || (ko == km && co < cm)) ? 1 : 0;
            }
            if (rank < KNN) idxOut[(size_t)r * KNN + rank] = (int)cm;
        }
    }
}

// ---------------- Kernel 5: u = A*x_point, v = (B-A)*x_point ----------------
__global__ __launch_bounds__(256) void k_uv(const float* __restrict__ x,
                                            const float* __restrict__ W1,
                                            float* __restrict__ u,
                                            float* __restrict__ v) {
    __shared__ float sA[64 * 33];
    __shared__ float sV[64 * 33];
    __shared__ float sxf[FDIM * 16];
    int t = threadIdx.x;
    for (int i = t; i < 64 * 32; i += 256) {
        int o = i >> 5, c = i & 31;
        float a = W1[o * 64 + c];
        sA[o * 33 + c] = a;
        sV[o * 33 + c] = W1[o * 64 + 32 + c] - a;
    }
    int p0 = blockIdx.x * 16;
    int b = p0 >> 13, nb = p0 & 8191;
    const float* xf = x + (size_t)b * FDIM * NPTS;
    for (int i = t; i < FDIM * 16; i += 256) {
        int f = i >> 4, p = i & 15;
        sxf[f * 16 + p] = xf[(size_t)f * NPTS + nb + p];
    }
    __syncthreads();
    #pragma unroll
    for (int ii = 0; ii < 4; ++ii) {
        int it = t + 256 * ii;
        int o = it & 63, p = it >> 6;
        float u0 = 0.f, u1 = 0.f, u2 = 0.f, w0 = 0.f, w1 = 0.f, w2 = 0.f;
        #pragma unroll
        for (int c = 0; c < 32; ++c) {
            float a = sA[o * 33 + c];
            float wv = sV[o * 33 + c];
            float x0 = sxf[(c * 3 + 0) * 16 + p];
            float x1 = sxf[(c * 3 + 1) * 16 + p];
            float x2 = sxf[(c * 3 + 2) * 16 + p];
            u0 += a * x0;  u1 += a * x1;  u2 += a * x2;
            w0 += wv * x0; w1 += wv * x1; w2 += wv * x2;
        }
        size_t base = ((size_t)(p0 + p) * 64 + o) * 3;
        u[base] = u0; u[base + 1] = u1; u[base + 2] = u2;
        v[base] = w0; v[base + 1] = w1; v[base + 2] = w2;
    }
}

// ---------------- Kernel 6: BN stats partials ----------------
__global__ __launch_bounds__(256) void k_stats(const float* __restrict__ u,
                                               const float* __restrict__ v,
                                               const int* __restrict__ idx,
                                               float* __restrict__ partial) {
    int blk = blockIdx.x, t = threadIdx.x;
    int o = t & 63, sub = t >> 6;
    int p0 = blk * 8;
    __shared__ float svf[8 * 192];
    __shared__ int sjf[8 * KNN];
    for (int i = t; i < 8 * 192; i += 256) svf[i] = v[(size_t)p0 * 192 + i];
    for (int i = t; i < 8 * KNN; i += 256) sjf[i] = idx[(size_t)p0 * KNN + i];
    __syncthreads();
    float s1 = 0.f, s2 = 0.f;
    for (int p = 0; p < 8; ++p) {
        int gpt = p0 + p;
        size_t ubase = (size_t)(gpt >> 13) * NPTS * 192;
        const float* vp = &svf[p * 192 + o * 3];
        float v0 = vp[0], v1 = vp[1], v2 = vp[2];
        for (int kk = sub; kk < KNN; kk += 4) {
            int j = sjf[p * KNN + kk];
            const float* up = u + ubase + (size_t)j * 192 + o * 3;
            float q0 = up[0] + v0, q1 = up[1] + v1, q2 = up[2] + v2;
            float nrm = sqrtf(q0 * q0 + q1 * q1 + q2 * q2) + VN_EPS;
            s1 += nrm;
            s2 += nrm * nrm;
        }
    }
    __shared__ float r1[256], r2[256];
    r1[t] = s1; r2[t] = s2;
    __syncthreads();
    if (t < 64) {
        float a1 = r1[t] + r1[t + 64] + r1[t + 128] + r1[t + 192];
        float a2 = r2[t] + r2[t + 64] + r2[t + 128] + r2[t + 192];
        partial[(size_t)blk * 128 + t] = a1;
        partial[(size_t)blk * 128 + 64 + t] = a2;
    }
}

// ---------------- Kernel 7: reduce stats -> gs, bs ----------------
__global__ __launch_bounds__(256) void k_reduce(const float* __restrict__ partial,
                                                const float* __restrict__ gamma,
                                                const float* __restrict__ beta,
                                                float* __restrict__ gsbs) {
    int ch = blockIdx.x, t = threadIdx.x;
    float s1 = 0.f, s2 = 0.f;
    for (int i = t; i < 2048; i += 256) {
        s1 += partial[(size_t)i * 128 + ch];
        s2 += partial[(size_t)i * 128 + 64 + ch];
    }
    __shared__ float r1[256], r2[256];
    r1[t] = s1; r2[t] = s2;
    __syncthreads();
    for (int s = 128; s > 0; s >>= 1) {
        if (t < s) { r1[t] += r1[t + s]; r2[t] += r2[t + s]; }
        __syncthreads();
    }
    if (t == 0) {
        const float cnt2 = (float)(NB * NPTS * KNN);
        float mean = r1[0] / cnt2;
        float var = r2[0] / cnt2 - mean * mean;
        float inv = 1.0f / sqrtf(var + VN_BN_EPS);
        float g = gamma[ch] * inv;
        gsbs[ch] = g;
        gsbs[64 + ch] = beta[ch] - mean * g;
    }
}

// ---------------- Kernel 8: fused BN + VN-LeakyReLU + mean, ONE WAVE per point ----------------
__global__ __launch_bounds__(64) void k_final(const float* __restrict__ u,
                                              const float* __restrict__ v,
                                              const int* __restrict__ idx,
                                              const float* __restrict__ Wd,
                                              const float* __restrict__ gsbs,
                                              float* __restrict__ out) {
    int lane = threadIdx.x;
    int l31 = lane & 31, hi = lane >> 5;
    int gpt = blockIdx.x;                         // global point b*N+n
    int b = gpt >> 13, n = gpt & 8191;

    __shared__ __align__(16) unsigned short Qw[30 * 72];  // f16
    __shared__ __align__(16) float Dw[30 * 64];           // f32

    f16x8 Bf[2][4];
    #pragma unroll
    for (int ct = 0; ct < 2; ++ct)
        #pragma unroll
        for (int ks = 0; ks < 4; ++ks) {
            const float* wp = Wd + (size_t)(ct * 32 + l31) * 64 + ks * 16 + hi * 8;
            f16x8 f;
            #pragma unroll
            for (int jj = 0; jj < 8; ++jj) f[jj] = (_Float16)wp[jj];
            Bf[ct][ks] = f;
        }

    float gso = gsbs[lane], bso = gsbs[64 + lane];
    size_t vb = (size_t)gpt * 192 + lane * 3;
    float v0 = v[vb], v1 = v[vb + 1], v2 = v[vb + 2];
    const int* jrow = idx + (size_t)gpt * KNN;
    size_t ubase = (size_t)b * NPTS * 192;
    float a0 = 0.f, a1 = 0.f, a2 = 0.f;

    for (int h = 0; h < 2; ++h) {
        #pragma unroll
        for (int kl = 0; kl < 10; ++kl) {
            int j = jrow[h * 10 + kl];
            const float* up = u + ubase + (size_t)j * 192 + lane * 3;
            float q0 = up[0] + v0, q1 = up[1] + v1, q2 = up[2] + v2;
            float nrm = sqrtf(q0 * q0 + q1 * q1 + q2 * q2) + VN_EPS;
            float f = (gso * nrm + bso) / nrm;
            q0 *= f; q1 *= f; q2 *= f;
            union { _Float16 f16; unsigned short u16; } c0, c1, c2;
            c0.f16 = (_Float16)q0; c1.f16 = (_Float16)q1; c2.f16 = (_Float16)q2;
            Qw[(3 * kl + 0) * 72 + lane] = c0.u16;
            Qw[(3 * kl + 1) * 72 + lane] = c1.u16;
            Qw[(3 * kl + 2) * 72 + lane] = c2.u16;
        }
        WAVESYNC();
        f32x16 acc[2];
        #pragma unroll
        for (int ct = 0; ct < 2; ++ct)
            #pragma unroll
            for (int e = 0; e < 16; ++e) acc[ct][e] = 0.f;
        #pragma unroll
        for (int ks = 0; ks < 4; ++ks) {
            f16x8 af = *(const f16x8*)&Qw[l31 * 72 + ks * 16 + hi * 8];
            acc[0] = __builtin_amdgcn_mfma_f32_32x32x16_f16(af, Bf[0][ks], acc[0], 0, 0, 0);
            acc[1] = __builtin_amdgcn_mfma_f32_32x32x16_f16(af, Bf[1][ks], acc[1], 0, 0, 0);
        }
        #pragma unroll
        for (int ct = 0; ct < 2; ++ct)
            #pragma unroll
            for (int q = 0; q < 4; ++q)
                #pragma unroll
                for (int r = 0; r < 4; ++r) {
                    int row = 4 * hi + 8 * q + r;
                    if (row < 30) Dw[row * 64 + ct * 32 + l31] = acc[ct][q * 4 + r];
                }
        WAVESYNC();
        #pragma unroll
        for (int kl = 0; kl < 10; ++kl) {
            float qd[3], dd[3];
            #pragma unroll
            for (int d = 0; d < 3; ++d) {
                union { unsigned short u16; _Float16 f16; } rr;
                rr.u16 = Qw[(3 * kl + d) * 72 + lane];
                qd[d] = (float)rr.f16;
                dd[d] = Dw[(3 * kl + d) * 64 + lane];
            }
            float dot = qd[0] * dd[0] + qd[1] * dd[1] + qd[2] * dd[2];
            float dn = dd[0] * dd[0] + dd[1] * dd[1] + dd[2] * dd[2];
            float coef = (dot >= 0.f) ? 0.f : 0.8f * dot / (dn + VN_EPS);
            a0 += qd[0] - coef * dd[0];
            a1 += qd[1] - coef * dd[1];
            a2 += qd[2] - coef * dd[2];
        }
        WAVESYNC();
    }
    float s = 1.f / (float)KNN;
    size_t ob = ((size_t)(b * 64 + lane) * 3) * NPTS + n;
    out[ob] = a0 * s;
    out[ob + NPTS] = a1 * s;
    out[ob + 2 * NPTS] = a2 * s;
}

// ---------------- host ----------------
extern "C" void kernel_launch(void* const* d_in, const int* in_sizes, int n_in,
                              void* d_out, int out_size, void* d_ws, size_t ws_size,
                              hipStream_t stream) {
    const float* x = (const float*)d_in[0];
    const float* W1 = (const float*)d_in[1];
    const float* Wd = (const float*)d_in[2];
    const float* gamma = (const float*)d_in[3];
    const float* beta = (const float*)d_in[4];
    float* out = (float*)d_out;

    char* ws = (char*)d_ws;
    size_t off = 0;
    auto alloc = [&](size_t bytes) {
        void* p = ws + off;
        off = (off + bytes + 255) & ~(size_t)255;
        return p;
    };
    const int totalRows = NB * NPTS;                 // 16384
    float* xxp = (float*)alloc((size_t)totalRows * 4);
    int* idxp = (int*)alloc((size_t)totalRows * KNN * 4);
    float* up = (float*)alloc((size_t)totalRows * 192 * 4);
    float* vp = (float*)alloc((size_t)totalRows * 192 * 4);
    float* partial = (float*)alloc((size_t)2048 * 128 * 4);
    float* gsbs = (float*)alloc(512);
    unsigned short* xsp = (unsigned short*)alloc((size_t)totalRows * 192 * 2);
    float* tauFp = (float*)alloc((size_t)totalRows * 4);
    unsigned* cnt2d = (unsigned*)alloc((size_t)totalRows * NPAN * 4);      // 4 MB
    unsigned* ovcnt = (unsigned*)alloc((size_t)totalRows * 4);             // 64 KB
    unsigned long long* ovbuf = (unsigned long long*)alloc((size_t)totalRows * OVCAP * 8); // 8 MB
    // union region: minibuf (50 MB) dead after k_thrsel; cand (101 MB) after
    void* region = alloc((size_t)totalRows * ROWSLOT * 8);
    float* minibuf = (float*)region;
    unsigned long long* cand = (unsigned long long*)region;

    hipMemsetAsync(ovcnt, 0, (size_t)totalRows * 4, stream);

    k_prep<<<totalRows / 256, 256, 0, stream>>>(x, xxp, xsp);

    k_thr<<<dim3(totalRows / 128, NSAMP / 128), 256, 0, stream>>>(xsp, xxp, minibuf);
    k_thrsel<<<totalRows / 4, 256, 0, stream>>>(minibuf, tauFp);
    k_distf<<<dim3(totalRows / 128, NPAN), 256, 0, stream>>>(xsp, xxp, tauFp,
                                                             cnt2d, cand, ovcnt, ovbuf);
    k_mrg<<<totalRows / 4, 256, 0, stream>>>(cand, cnt2d, ovcnt, ovbuf, idxp);

    k_uv<<<totalRows / 16, 256, 0, stream>>>(x, W1, up, vp);
    k_stats<<<totalRows / 8, 256, 0, stream>>>(up, vp, idxp, partial);
    k_reduce<<<64, 256, 0, stream>>>(partial, gamma, beta, gsbs);
    k_final<<<totalRows, 64, 0, stream>>>(up, vp, idxp, Wd, gsbs, out);
}

// Round 23
// 390.121 us; speedup vs baseline: 1.0655x; 1.0655x over previous
//
#include <hip/hip_runtime.h>
#include <math.h>

#define NPTS 8192
#define NB 2
#define FDIM 96
#define KNN 20
#define VN_EPS 1e-6f
#define VN_BN_EPS 1e-5f
#define NSAMP 768           // sampled cols for threshold estimate
#define PSLOT 12            // candidate slots per (row, 128-col panel), mean ~3.4
#define NPAN 64             // NPTS / 128
#define ROWSLOT (NPAN * PSLOT)   // 768 slots per row
#define CAPS 12             // ROWSLOT / 64
#define OVCAP 64            // per-row overflow spill slots

typedef float f32x16 __attribute__((ext_vector_type(16)));
typedef _Float16 f16x8 __attribute__((ext_vector_type(8)));
typedef unsigned short u16x8 __attribute__((ext_vector_type(8)));

#define WAVESYNC()                                            \
    do {                                                      \
        asm volatile("s_waitcnt lgkmcnt(0)" ::: "memory");    \
        __builtin_amdgcn_wave_barrier();                      \
        asm volatile("" ::: "memory");                        \
    } while (0)

__device__ __forceinline__ unsigned orderable(float v) {
    unsigned u = __float_as_uint(v);
    return (u & 0x80000000u) ? ~u : (u | 0x80000000u);
}
__device__ __forceinline__ float unorderable(unsigned k) {
    unsigned u = (k & 0x80000000u) ? (k & 0x7fffffffu) : ~k;
    return __uint_as_float(u);
}

// ---------------- Kernel 1: xx = sum_f xf^2  AND  xs = f16 split table ----------------
__global__ __launch_bounds__(256) void k_prep(const float* __restrict__ x,
                                              float* __restrict__ xx,
                                              unsigned short* __restrict__ xs) {
    int m = blockIdx.x * 256 + threadIdx.x;
    int b = m >> 13, n = m & 8191;
    const float* xf = x + (size_t)b * FDIM * NPTS;
    unsigned short* row = xs + (size_t)m * 192;
    float s = 0.f;
    for (int fc = 0; fc < 12; ++fc) {
        u16x8 hv, lv;
        #pragma unroll
        for (int j = 0; j < 8; ++j) {
            float vv = xf[(size_t)(fc * 8 + j) * NPTS + n];
            s += vv * vv;
            _Float16 h = (_Float16)vv;
            float hf = (float)h;
            _Float16 l = (_Float16)(vv - hf);
            union { _Float16 f; unsigned short u; } ch, cl;
            ch.f = h; cl.f = l;
            hv[j] = ch.u; lv[j] = cl.u;
        }
        *(u16x8*)(row + fc * 8) = hv;
        *(u16x8*)(row + 96 + fc * 8) = lv;
    }
    xx[m] = s;
}

// ================= shared GEMM structure (k_thr / k_distf), 128x128 tile =================
// 4 waves x 32 rows x 128 cols. A-hi in regs, A-lo reloaded after pass 2.
// Pass chain per value: hl, hh, lh -> bitwise-identical between k_thr and k_distf.
// launch_bounds stays (256,3): natural reg footprint ~148 (84 arch + 64 acc);
// tighter bound spills accumulators to scratch (R20: 6x regression).
// Epilogue MUST keep ballot/prefix slot assignment: consecutive lanes -> consecutive
// slots = coalesced cand writes (R22's LDS-counter variant: WRITE 61->170 MB, +13%).

// ---------------- Kernel 2a: sampled neg-dist (cols 0..767) -> minibuf ----------------
__global__ __launch_bounds__(256, 3) void k_thr(const unsigned short* __restrict__ xs,
                                                const float* __restrict__ xx,
                                                float* __restrict__ minibuf) {
    __shared__ __align__(16) unsigned short Bsl[128][104];
    __shared__ float sxr[128];
    __shared__ float sxc[128];
    int t = threadIdx.x;
    int lane = t & 63, wid = t >> 6;
    int l31 = lane & 31, hi = lane >> 5;
    int row0 = blockIdx.x * 128;
    int b = row0 >> 13;
    int panel = blockIdx.y;                  // 0..5
    int m0 = panel * 128;
    const unsigned short* xsb = xs + (size_t)b * NPTS * 192;
    int n0w = (row0 & 8191) + wid * 32;

    f16x8 af[6];
    const unsigned short* arow = xsb + (size_t)(n0w + l31) * 192 + hi * 8;
    #pragma unroll
    for (int ks = 0; ks < 6; ++ks) af[ks] = *(const f16x8*)(arow + ks * 16);   // A-hi

    if (t < 128) {
        sxr[t] = xx[row0 + t];
        sxc[t] = xx[(b << 13) + m0 + t];
    }

    f32x16 acc[4];
    #pragma unroll
    for (int ct = 0; ct < 4; ++ct)
        #pragma unroll
        for (int e = 0; e < 16; ++e) acc[ct][e] = 0.f;

    int sc2 = t >> 1, sh2 = t & 1;
    auto stageB = [&](int part) {
        const unsigned short* sb = xsb + (size_t)(m0 + sc2) * 192 + part * 96 + sh2 * 48;
        unsigned short* db = &Bsl[sc2][sh2 * 48];
        #pragma unroll
        for (int j = 0; j < 6; ++j) *(u16x8*)(db + j * 8) = *(const u16x8*)(sb + j * 8);
    };
    auto mmpass = [&]() {
        #pragma unroll
        for (int ks = 0; ks < 6; ++ks)
            #pragma unroll
            for (int ct = 0; ct < 4; ++ct) {
                f16x8 bf = *(const f16x8*)&Bsl[ct * 32 + l31][ks * 16 + hi * 8];
                acc[ct] = __builtin_amdgcn_mfma_f32_32x32x16_f16(af[ks], bf, acc[ct], 0, 0, 0);
            }
    };

    stageB(1);                   // B lo
    __syncthreads();
    mmpass();                    // hA*lB
    __syncthreads();
    stageB(0);                   // B hi
    __syncthreads();
    mmpass();                    // hA*hB
    #pragma unroll
    for (int ks = 0; ks < 6; ++ks) af[ks] = *(const f16x8*)(arow + 96 + ks * 16);  // A-lo
    mmpass();                    // lA*hB

    float xc[4];
    #pragma unroll
    for (int ct = 0; ct < 4; ++ct) xc[ct] = sxc[ct * 32 + l31];
    #pragma unroll
    for (int q = 0; q < 4; ++q)
        #pragma unroll
        for (int rr = 0; rr < 4; ++rr) {
            int rowin = wid * 32 + 4 * hi + 8 * q + rr;
            float xr = sxr[rowin];
            #pragma unroll
            for (int ct = 0; ct < 4; ++ct) {
                float valx = 2.f * acc[ct][q * 4 + rr] - xr - xc[ct];
                minibuf[(size_t)(row0 + rowin) * NSAMP + m0 + ct * 32 + l31] = valx;
            }
        }
}

// ---------------- Kernel 2b: per-row threshold (float form) from sample ----------------
__global__ __launch_bounds__(256) void k_thrsel(const float* __restrict__ minibuf,
                                                float* __restrict__ tauF) {
    int t = threadIdx.x;
    int lane = t & 63, w = t >> 6;
    int r = blockIdx.x * 4 + w;
    const float* mp = minibuf + (size_t)r * NSAMP;
    unsigned key[12];
    #pragma unroll
    for (int s = 0; s < 12; ++s) key[s] = orderable(mp[lane + s * 64]);
    unsigned lo = 0, hi = 0x10000u;
    for (int it = 0; it < 16; ++it) {
        unsigned mid = (lo + hi) >> 1;
        unsigned mkey = mid << 16;
        int c = 0;
        #pragma unroll
        for (int s = 0; s < 12; ++s) c += (key[s] >= mkey) ? 1 : 0;
        #pragma unroll
        for (int d = 1; d < 64; d <<= 1) c += __shfl_xor(c, d);
        if (c >= KNN) lo = mid; else hi = mid;
    }
    if (lane == 0) tauF[r] = unorderable(lo << 16);
}

// ---------------- Kernel 3: full neg-dist + static-region filter (128x128 tile) ----------------
// Float-space compare on hot path; ballot -> popc rank -> fixed 12-slot (row,panel)
// region (coalesced writes); rare overflow spills via per-row atomic valve.
__global__ __launch_bounds__(256, 3) void k_distf(const unsigned short* __restrict__ xs,
                                                  const float* __restrict__ xx,
                                                  const float* __restrict__ tauF,
                                                  unsigned* __restrict__ cnt2d,
                                                  unsigned long long* __restrict__ cand,
                                                  unsigned* __restrict__ ovcnt,
                                                  unsigned long long* __restrict__ ovbuf) {
    __shared__ __align__(16) unsigned short Bsl[128][104];
    __shared__ float sxr[128];
    __shared__ float sxc[128];
    __shared__ float stau[128];
    int t = threadIdx.x;
    int lane = t & 63, wid = t >> 6;
    int l31 = lane & 31, hi = lane >> 5;
    int row0 = blockIdx.x * 128;
    int b = row0 >> 13;
    int panel = blockIdx.y;                  // 0..63
    int m0 = panel * 128;
    const unsigned short* xsb = xs + (size_t)b * NPTS * 192;
    int n0w = (row0 & 8191) + wid * 32;

    f16x8 af[6];
    const unsigned short* arow = xsb + (size_t)(n0w + l31) * 192 + hi * 8;
    #pragma unroll
    for (int ks = 0; ks < 6; ++ks) af[ks] = *(const f16x8*)(arow + ks * 16);   // A-hi

    if (t < 128) {
        sxr[t] = xx[row0 + t];
        stau[t] = tauF[row0 + t];
        sxc[t] = xx[(b << 13) + m0 + t];
    }

    f32x16 acc[4];
    #pragma unroll
    for (int ct = 0; ct < 4; ++ct)
        #pragma unroll
        for (int e = 0; e < 16; ++e) acc[ct][e] = 0.f;

    int sc2 = t >> 1, sh2 = t & 1;
    auto stageB = [&](int part) {
        const unsigned short* sb = xsb + (size_t)(m0 + sc2) * 192 + part * 96 + sh2 * 48;
        unsigned short* db = &Bsl[sc2][sh2 * 48];
        #pragma unroll
        for (int j = 0; j < 6; ++j) *(u16x8*)(db + j * 8) = *(const u16x8*)(sb + j * 8);
    };
    auto mmpass = [&]() {
        #pragma unroll
        for (int ks = 0; ks < 6; ++ks)
            #pragma unroll
            for (int ct = 0; ct < 4; ++ct) {
                f16x8 bf = *(const f16x8*)&Bsl[ct * 32 + l31][ks * 16 + hi * 8];
                acc[ct] = __builtin_amdgcn_mfma_f32_32x32x16_f16(af[ks], bf, acc[ct], 0, 0, 0);
            }
    };

    stageB(1);                   // B lo
    __syncthreads();
    mmpass();                    // hA*lB
    __syncthreads();
    stageB(0);                   // B hi
    __syncthreads();
    mmpass();                    // hA*hB
    #pragma unroll
    for (int ks = 0; ks < 6; ++ks) af[ks] = *(const f16x8*)(arow + 96 + ks * 16);  // A-lo
    mmpass();                    // lA*hB

    float xc[4];
    #pragma unroll
    for (int ct = 0; ct < 4; ++ct) xc[ct] = sxc[ct * 32 + l31];
    #pragma unroll
    for (int q = 0; q < 4; ++q)
        #pragma unroll
        for (int rr = 0; rr < 4; ++rr) {
            int rowin = wid * 32 + 4 * hi + 8 * q + rr;
            int grow = row0 + rowin;
            float xr = sxr[rowin];
            float tau = stau[rowin];
            unsigned cnt_run = 0;
            size_t base = (size_t)grow * ROWSLOT + (size_t)panel * PSLOT;
            #pragma unroll
            for (int ct = 0; ct < 4; ++ct) {
                float valx = 2.f * acc[ct][q * 4 + rr] - xr - xc[ct];
                bool p = (valx >= tau);
                unsigned long long bal = __ballot(p);
                unsigned hm = hi ? (unsigned)(bal >> 32) : (unsigned)bal;
                if (p) {
                    unsigned key = orderable(valx);
                    unsigned pos = cnt_run + (unsigned)__popc(hm & ((1u << l31) - 1u));
                    unsigned long long e = ((unsigned long long)key << 32)
                                         | (unsigned)(m0 + ct * 32 + l31);
                    if (pos < PSLOT) {
                        cand[base + pos] = e;
                    } else {            // rare spill: exactness valve
                        unsigned o = atomicAdd(&ovcnt[grow], 1u);
                        if (o < OVCAP) ovbuf[(size_t)grow * OVCAP + o] = e;
                    }
                }
                cnt_run += (unsigned)__popc(hm);
            }
            if (l31 == 0)
                cnt2d[(size_t)grow * NPAN + panel] = (cnt_run < PSLOT) ? cnt_run : PSLOT;
        }
}

// ---------------- Kernel 4: merge candidates + spills -> exact top-20 ----------------
__global__ __launch_bounds__(256) void k_mrg(const unsigned long long* __restrict__ cand,
                                             const unsigned* __restrict__ cnt2d,
                                             const unsigned* __restrict__ ovcnt,
                                             const unsigned long long* __restrict__ ovbuf,
                                             int* __restrict__ idxOut) {
    int t = threadIdx.x;
    int lane = t & 63, w = t >> 6;
    int r = blockIdx.x * 4 + w;
    __shared__ unsigned scc[4][NPAN];
    scc[w][lane] = cnt2d[(size_t)r * NPAN + lane];      // NPAN == 64 == wave size
    WAVESYNC();
    const unsigned long long* cp = cand + (size_t)r * ROWSLOT;
    unsigned long long pk[CAPS + 1];
    #pragma unroll
    for (int s = 0; s < CAPS; ++s) {
        int slot = lane + 64 * s;
        int panel = slot / PSLOT;
        int within = slot - panel * PSLOT;
        pk[s] = (within < (int)scc[w][panel]) ? cp[slot] : 0ull;   // key 0 << real keys
    }
    int ovn = (int)ovcnt[r]; if (ovn > OVCAP) ovn = OVCAP;
    pk[CAPS] = (lane < ovn) ? ovbuf[(size_t)r * OVCAP + lane] : 0ull;

    unsigned lo = 0, hi = 0x10000u;
    for (int it = 0; it < 16; ++it) {
        unsigned mid = (lo + hi) >> 1;
        unsigned mkey = mid << 16;
        int c = 0;
        #pragma unroll
        for (int s = 0; s <= CAPS; ++s) c += ((unsigned)(pk[s] >> 32) >= mkey) ? 1 : 0;
        #pragma unroll
        for (int d = 1; d < 64; d <<= 1) c += __shfl_xor(c, d);
        if (c >= KNN) lo = mid; else hi = mid;
    }
    unsigned thr = lo << 16;

    __shared__ unsigned long long sk[4][128];
    __shared__ int sn[4];
    if (lane == 0) sn[w] = 0;
    WAVESYNC();
    #pragma unroll
    for (int s = 0; s <= CAPS; ++s) {
        if ((unsigned)(pk[s] >> 32) >= thr) {
            int j = atomicAdd(&sn[w], 1);
            if (j < 128) sk[w][j] = pk[s];
        }
    }
    WAVESYNC();
    int nc = sn[w]; if (nc > 128) nc = 128;
    #pragma unroll
    for (int half = 0; half < 2; ++half) {
        int i = lane + half * 64;
        if (i < nc) {
            unsigned long long me = sk[w][i];
            unsigned km = (unsigned)(me >> 32), cm = (unsigned)me;
            int rank = 0;
            for (int j = 0; j < nc; ++j) {
                unsigned long long o = sk[w][j];
                unsigned ko = (unsigned)(o >> 32), co = (unsigned)o;
                rank += (ko > km || (ko == km && co < cm)) ? 1 : 0;
            }
            if (rank < KNN) idxOut[(size_t)r * KNN + rank] = (int)cm;
        }
    }
}

// ---------------- Kernel 5: u = A*x_point, v = (B-A)*x_point ----------------
__global__ __launch_bounds__(256) void k_uv(const float* __restrict__ x,
                                            const float* __restrict__ W1,
                                            float* __restrict__ u,
                                            float* __restrict__ v) {
    __shared__ float sA[64 * 33];
    __shared__ float sV[64 * 33];
    __shared__ float sxf[FDIM * 16];
    int t = threadIdx.x;
    for (int i = t; i < 64 * 32; i += 256) {
        int o = i >> 5, c = i & 31;
        float a = W1[o * 64 + c];
        sA[o * 33 + c] = a;
        sV[o * 33 + c] = W1[o * 64 + 32 + c] - a;
    }
    int p0 = blockIdx.x * 16;
    int b = p0 >> 13, nb = p0 & 8191;
    const float* xf = x + (size_t)b * FDIM * NPTS;
    for (int i = t; i < FDIM * 16; i += 256) {
        int f = i >> 4, p = i & 15;
        sxf[f * 16 + p] = xf[(size_t)f * NPTS + nb + p];
    }
    __syncthreads();
    #pragma unroll
    for (int ii = 0; ii < 4; ++ii) {
        int it = t + 256 * ii;
        int o = it & 63, p = it >> 6;
        float u0 = 0.f, u1 = 0.f, u2 = 0.f, w0 = 0.f, w1 = 0.f, w2 = 0.f;
        #pragma unroll
        for (int c = 0; c < 32; ++c) {
            float a = sA[o * 33 + c];
            float wv = sV[o * 33 + c];
            float x0 = sxf[(c * 3 + 0) * 16 + p];
            float x1 = sxf[(c * 3 + 1) * 16 + p];
            float x2 = sxf[(c * 3 + 2) * 16 + p];
            u0 += a * x0;  u1 += a * x1;  u2 += a * x2;
            w0 += wv * x0; w1 += wv * x1; w2 += wv * x2;
        }
        size_t base = ((size_t)(p0 + p) * 64 + o) * 3;
        u[base] = u0; u[base + 1] = u1; u[base + 2] = u2;
        v[base] = w0; v[base + 1] = w1; v[base + 2] = w2;
    }
}

// ---------------- Kernel 6: BN stats partials ----------------
__global__ __launch_bounds__(256) void k_stats(const float* __restrict__ u,
                                               const float* __restrict__ v,
                                               const int* __restrict__ idx,
                                               float* __restrict__ partial) {
    int blk = blockIdx.x, t = threadIdx.x;
    int o = t & 63, sub = t >> 6;
    int p0 = blk * 8;
    __shared__ float svf[8 * 192];
    __shared__ int sjf[8 * KNN];
    for (int i = t; i < 8 * 192; i += 256) svf[i] = v[(size_t)p0 * 192 + i];
    for (int i = t; i < 8 * KNN; i += 256) sjf[i] = idx[(size_t)p0 * KNN + i];
    __syncthreads();
    float s1 = 0.f, s2 = 0.f;
    for (int p = 0; p < 8; ++p) {
        int gpt = p0 + p;
        size_t ubase = (size_t)(gpt >> 13) * NPTS * 192;
        const float* vp = &svf[p * 192 + o * 3];
        float v0 = vp[0], v1 = vp[1], v2 = vp[2];
        for (int kk = sub; kk < KNN; kk += 4) {
            int j = sjf[p * KNN + kk];
            const float* up = u + ubase + (size_t)j * 192 + o * 3;
            float q0 = up[0] + v0, q1 = up[1] + v1, q2 = up[2] + v2;
            float nrm = sqrtf(q0 * q0 + q1 * q1 + q2 * q2) + VN_EPS;
            s1 += nrm;
            s2 += nrm * nrm;
        }
    }
    __shared__ float r1[256], r2[256];
    r1[t] = s1; r2[t] = s2;
    __syncthreads();
    if (t < 64) {
        float a1 = r1[t] + r1[t + 64] + r1[t + 128] + r1[t + 192];
        float a2 = r2[t] + r2[t + 64] + r2[t + 128] + r2[t + 192];
        partial[(size_t)blk * 128 + t] = a1;
        partial[(size_t)blk * 128 + 64 + t] = a2;
    }
}

// ---------------- Kernel 7: reduce stats -> gs, bs ----------------
__global__ __launch_bounds__(256) void k_reduce(const float* __restrict__ partial,
                                                const float* __restrict__ gamma,
                                                const float* __restrict__ beta,
                                                float* __restrict__ gsbs) {
    int ch = blockIdx.x, t = threadIdx.x;
    float s1 = 0.f, s2 = 0.f;
    for (int i = t; i < 2048; i += 256) {
        s1 += partial[(size_t)i * 128 + ch];
        s2 += partial[(size_t)i * 128 + 64 + ch];
    }
    __shared__ float r1[256], r2[256];
    r1[t] = s1; r2[t] = s2;
    __syncthreads();
    for (int s = 128; s > 0; s >>= 1) {
        if (t < s) { r1[t] += r1[t + s]; r2[t] += r2[t + s]; }
        __syncthreads();
    }
    if (t == 0) {
        const float cnt2 = (float)(NB * NPTS * KNN);
        float mean = r1[0] / cnt2;
        float var = r2[0] / cnt2 - mean * mean;
        float inv = 1.0f / sqrtf(var + VN_BN_EPS);
        float g = gamma[ch] * inv;
        gsbs[ch] = g;
        gsbs[64 + ch] = beta[ch] - mean * g;
    }
}

// ---------------- Kernel 8: fused BN + VN-LeakyReLU + mean, ONE WAVE per point ----------------
__global__ __launch_bounds__(64) void k_final(const float* __restrict__ u,
                                              const float* __restrict__ v,
                                              const int* __restrict__ idx,
                                              const float* __restrict__ Wd,
                                              const float* __restrict__ gsbs,
                                              float* __restrict__ out) {
    int lane = threadIdx.x;
    int l31 = lane & 31, hi = lane >> 5;
    int gpt = blockIdx.x;                         // global point b*N+n
    int b = gpt >> 13, n = gpt & 8191;

    __shared__ __align__(16) unsigned short Qw[30 * 72];  // f16
    __shared__ __align__(16) float Dw[30 * 64];           // f32

    f16x8 Bf[2][4];
    #pragma unroll
    for (int ct = 0; ct < 2; ++ct)
        #pragma unroll
        for (int ks = 0; ks < 4; ++ks) {
            const float* wp = Wd + (size_t)(ct * 32 + l31) * 64 + ks * 16 + hi * 8;
            f16x8 f;
            #pragma unroll
            for (int jj = 0; jj < 8; ++jj) f[jj] = (_Float16)wp[jj];
            Bf[ct][ks] = f;
        }

    float gso = gsbs[lane], bso = gsbs[64 + lane];
    size_t vb = (size_t)gpt * 192 + lane * 3;
    float v0 = v[vb], v1 = v[vb + 1], v2 = v[vb + 2];
    const int* jrow = idx + (size_t)gpt * KNN;
    size_t ubase = (size_t)b * NPTS * 192;
    float a0 = 0.f, a1 = 0.f, a2 = 0.f;

    for (int h = 0; h < 2; ++h) {
        #pragma unroll
        for (int kl = 0; kl < 10; ++kl) {
            int j = jrow[h * 10 + kl];
            const float* up = u + ubase + (size_t)j * 192 + lane * 3;
            float q0 = up[0] + v0, q1 = up[1] + v1, q2 = up[2] + v2;
            float nrm = sqrtf(q0 * q0 + q1 * q1 + q2 * q2) + VN_EPS;
            float f = (gso * nrm + bso) / nrm;
            q0 *= f; q1 *= f; q2 *= f;
            union { _Float16 f16; unsigned short u16; } c0, c1, c2;
            c0.f16 = (_Float16)q0; c1.f16 = (_Float16)q1; c2.f16 = (_Float16)q2;
            Qw[(3 * kl + 0) * 72 + lane] = c0.u16;
            Qw[(3 * kl + 1) * 72 + lane] = c1.u16;
            Qw[(3 * kl + 2) * 72 + lane] = c2.u16;
        }
        WAVESYNC();
        f32x16 acc[2];
        #pragma unroll
        for (int ct = 0; ct < 2; ++ct)
            #pragma unroll
            for (int e = 0; e < 16; ++e) acc[ct][e] = 0.f;
        #pragma unroll
        for (int ks = 0; ks < 4; ++ks) {
            f16x8 af = *(const f16x8*)&Qw[l31 * 72 + ks * 16 + hi * 8];
            acc[0] = __builtin_amdgcn_mfma_f32_32x32x16_f16(af, Bf[0][ks], acc[0], 0, 0, 0);
            acc[1] = __builtin_amdgcn_mfma_f32_32x32x16_f16(af, Bf[1][ks], acc[1], 0, 0, 0);
        }
        #pragma unroll
        for (int ct = 0; ct < 2; ++ct)
            #pragma unroll
            for (int q = 0; q < 4; ++q)
                #pragma unroll
                for (int r = 0; r < 4; ++r) {
                    int row = 4 * hi + 8 * q + r;
                    if (row < 30) Dw[row * 64 + ct * 32 + l31] = acc[ct][q * 4 + r];
                }
        WAVESYNC();
        #pragma unroll
        for (int kl = 0; kl < 10; ++kl) {
            float qd[3], dd[3];
            #pragma unroll
            for (int d = 0; d < 3; ++d) {
                union { unsigned short u16; _Float16 f16; } rr;
                rr.u16 = Qw[(3 * kl + d) * 72 + lane];
                qd[d] = (float)rr.f16;
                dd[d] = Dw[(3 * kl + d) * 64 + lane];
            }
            float dot = qd[0] * dd[0] + qd[1] * dd[1] + qd[2] * dd[2];
            float dn = dd[0] * dd[0] + dd[1] * dd[1] + dd[2] * dd[2];
            float coef = (dot >= 0.f) ? 0.f : 0.8f * dot / (dn + VN_EPS);
            a0 += qd[0] - coef * dd[0];
            a1 += qd[1] - coef * dd[1];
            a2 += qd[2] - coef * dd[2];
        }
        WAVESYNC();
    }
    float s = 1.f / (float)KNN;
    size_t ob = ((size_t)(b * 64 + lane) * 3) * NPTS + n;
    out[ob] = a0 * s;
    out[ob + NPTS] = a1 * s;
    out[ob + 2 * NPTS] = a2 * s;
}

// ---------------- host ----------------
extern "C" void kernel_launch(void* const* d_in, const int* in_sizes, int n_in,
                              void* d_out, int out_size, void* d_ws, size_t ws_size,
                              hipStream_t stream) {
    const float* x = (const float*)d_in[0];
    const float* W1 = (const float*)d_in[1];
    const float* Wd = (const float*)d_in[2];
    const float* gamma = (const float*)d_in[3];
    const float* beta = (const float*)d_in[4];
    float* out = (float*)d_out;

    char* ws = (char*)d_ws;
    size_t off = 0;
    auto alloc = [&](size_t bytes) {
        void* p = ws + off;
        off = (off + bytes + 255) & ~(size_t)255;
        return p;
    };
    const int totalRows = NB * NPTS;                 // 16384
    float* xxp = (float*)alloc((size_t)totalRows * 4);
    int* idxp = (int*)alloc((size_t)totalRows * KNN * 4);
    float* up = (float*)alloc((size_t)totalRows * 192 * 4);
    float* vp = (float*)alloc((size_t)totalRows * 192 * 4);
    float* partial = (float*)alloc((size_t)2048 * 128 * 4);
    float* gsbs = (float*)alloc(512);
    unsigned short* xsp = (unsigned short*)alloc((size_t)totalRows * 192 * 2);
    float* tauFp = (float*)alloc((size_t)totalRows * 4);
    unsigned* cnt2d = (unsigned*)alloc((size_t)totalRows * NPAN * 4);      // 4 MB
    unsigned* ovcnt = (unsigned*)alloc((size_t)totalRows * 4);             // 64 KB
    unsigned long long* ovbuf = (unsigned long long*)alloc((size_t)totalRows * OVCAP * 8); // 8 MB
    // union region: minibuf (50 MB) dead after k_thrsel; cand (101 MB) after
    void* region = alloc((size_t)totalRows * ROWSLOT * 8);
    float* minibuf = (float*)region;
    unsigned long long* cand = (unsigned long long*)region;

    hipMemsetAsync(ovcnt, 0, (size_t)totalRows * 4, stream);

    k_prep<<<totalRows / 256, 256, 0, stream>>>(x, xxp, xsp);

    k_thr<<<dim3(totalRows / 128, NSAMP / 128), 256, 0, stream>>>(xsp, xxp, minibuf);
    k_thrsel<<<totalRows / 4, 256, 0, stream>>>(minibuf, tauFp);
    k_distf<<<dim3(totalRows / 128, NPAN), 256, 0, stream>>>(xsp, xxp, tauFp,
                                                             cnt2d, cand, ovcnt, ovbuf);
    k_mrg<<<totalRows / 4, 256, 0, stream>>>(cand, cnt2d, ovcnt, ovbuf, idxp);

    k_uv<<<totalRows / 16, 256, 0, stream>>>(x, W1, up, vp);
    k_stats<<<totalRows / 8, 256, 0, stream>>>(up, vp, idxp, partial);
    k_reduce<<<64, 256, 0, stream>>>(partial, gamma, beta, gsbs);
    k_final<<<totalRows, 64, 0, stream>>>(up, vp, idxp, Wd, gsbs, out);
}

// Round 25
// 386.241 us; speedup vs baseline: 1.0762x; 1.0100x over previous
//
#include <hip/hip_runtime.h>
#include <math.h>

#define NPTS 8192
#define NB 2
#define FDIM 96
#define KNN 20
#define VN_EPS 1e-6f
#define VN_BN_EPS 1e-5f
#define NSAMP 768           // sampled cols for threshold estimate
#define PSLOT 12            // candidate slots per (row, 128-col panel)
#define NPAN 64             // NPTS / 128
#define ROWSLOT (NPAN * PSLOT)   // 768 slots per row
#define CAPS 12             // ROWSLOT / 64
#define OVCAP 64            // per-row overflow spill slots
#define TSLOT 3             // transposed slots per (row, panel, wave)
#define NTILE 2080          // 64*65/2 upper-triangle tiles per batch

typedef float f32x16 __attribute__((ext_vector_type(16)));
typedef _Float16 f16x8 __attribute__((ext_vector_type(8)));
typedef unsigned short u16x8 __attribute__((ext_vector_type(8)));

#define WAVESYNC()                                            \
    do {                                                      \
        asm volatile("s_waitcnt lgkmcnt(0)" ::: "memory");    \
        __builtin_amdgcn_wave_barrier();                      \
        asm volatile("" ::: "memory");                        \
    } while (0)

__device__ __forceinline__ unsigned orderable(float v) {
    unsigned u = __float_as_uint(v);
    return (u & 0x80000000u) ? ~u : (u | 0x80000000u);
}
__device__ __forceinline__ float unorderable(unsigned k) {
    unsigned u = (k & 0x80000000u) ? (k & 0x7fffffffu) : ~k;
    return __uint_as_float(u);
}

// ---------------- Kernel 1: xx = sum_f xf^2  AND  xs = f16 split table ----------------
__global__ __launch_bounds__(256) void k_prep(const float* __restrict__ x,
                                              float* __restrict__ xx,
                                              unsigned short* __restrict__ xs) {
    int m = blockIdx.x * 256 + threadIdx.x;
    int b = m >> 13, n = m & 8191;
    const float* xf = x + (size_t)b * FDIM * NPTS;
    unsigned short* row = xs + (size_t)m * 192;
    float s = 0.f;
    for (int fc = 0; fc < 12; ++fc) {
        u16x8 hv, lv;
        #pragma unroll
        for (int j = 0; j < 8; ++j) {
            float vv = xf[(size_t)(fc * 8 + j) * NPTS + n];
            s += vv * vv;
            _Float16 h = (_Float16)vv;
            float hf = (float)h;
            _Float16 l = (_Float16)(vv - hf);
            union { _Float16 f; unsigned short u; } ch, cl;
            ch.f = h; cl.f = l;
            hv[j] = ch.u; lv[j] = cl.u;
        }
        *(u16x8*)(row + fc * 8) = hv;
        *(u16x8*)(row + 96 + fc * 8) = lv;
    }
    xx[m] = s;
}

// ---------------- Kernel 2a: sampled neg-dist (cols 0..767) -> minibuf ----------------
__global__ __launch_bounds__(256, 3) void k_thr(const unsigned short* __restrict__ xs,
                                                const float* __restrict__ xx,
                                                float* __restrict__ minibuf) {
    __shared__ __align__(16) unsigned short Bsl[128][104];
    __shared__ float sxr[128];
    __shared__ float sxc[128];
    int t = threadIdx.x;
    int lane = t & 63, wid = t >> 6;
    int l31 = lane & 31, hi = lane >> 5;
    int row0 = blockIdx.x * 128;
    int b = row0 >> 13;
    int panel = blockIdx.y;                  // 0..5
    int m0 = panel * 128;
    const unsigned short* xsb = xs + (size_t)b * NPTS * 192;
    int n0w = (row0 & 8191) + wid * 32;

    f16x8 af[6];
    const unsigned short* arow = xsb + (size_t)(n0w + l31) * 192 + hi * 8;
    #pragma unroll
    for (int ks = 0; ks < 6; ++ks) af[ks] = *(const f16x8*)(arow + ks * 16);   // A-hi

    if (t < 128) {
        sxr[t] = xx[row0 + t];
        sxc[t] = xx[(b << 13) + m0 + t];
    }

    f32x16 acc[4];
    #pragma unroll
    for (int ct = 0; ct < 4; ++ct)
        #pragma unroll
        for (int e = 0; e < 16; ++e) acc[ct][e] = 0.f;

    int sc2 = t >> 1, sh2 = t & 1;
    auto stageB = [&](int part) {
        const unsigned short* sb = xsb + (size_t)(m0 + sc2) * 192 + part * 96 + sh2 * 48;
        unsigned short* db = &Bsl[sc2][sh2 * 48];
        #pragma unroll
        for (int j = 0; j < 6; ++j) *(u16x8*)(db + j * 8) = *(const u16x8*)(sb + j * 8);
    };
    auto mmpass = [&]() {
        #pragma unroll
        for (int ks = 0; ks < 6; ++ks)
            #pragma unroll
            for (int ct = 0; ct < 4; ++ct) {
                f16x8 bf = *(const f16x8*)&Bsl[ct * 32 + l31][ks * 16 + hi * 8];
                acc[ct] = __builtin_amdgcn_mfma_f32_32x32x16_f16(af[ks], bf, acc[ct], 0, 0, 0);
            }
    };

    stageB(1);                   // B lo
    __syncthreads();
    mmpass();                    // hA*lB
    __syncthreads();
    stageB(0);                   // B hi
    __syncthreads();
    mmpass();                    // hA*hB
    #pragma unroll
    for (int ks = 0; ks < 6; ++ks) af[ks] = *(const f16x8*)(arow + 96 + ks * 16);  // A-lo
    mmpass();                    // lA*hB

    float xc[4];
    #pragma unroll
    for (int ct = 0; ct < 4; ++ct) xc[ct] = sxc[ct * 32 + l31];
    #pragma unroll
    for (int q = 0; q < 4; ++q)
        #pragma unroll
        for (int rr = 0; rr < 4; ++rr) {
            int rowin = wid * 32 + 4 * hi + 8 * q + rr;
            float xr = sxr[rowin];
            #pragma unroll
            for (int ct = 0; ct < 4; ++ct) {
                float valx = 2.f * acc[ct][q * 4 + rr] - xr - xc[ct];
                minibuf[(size_t)(row0 + rowin) * NSAMP + m0 + ct * 32 + l31] = valx;
            }
        }
}

// ---------------- Kernel 2b: per-row threshold with one extra 2^16 slack step ----------------
// Slack covers the +-few-ulp asymmetry of transposed-sourced values in k_distf.
__global__ __launch_bounds__(256) void k_thrsel(const float* __restrict__ minibuf,
                                                float* __restrict__ tauF) {
    int t = threadIdx.x;
    int lane = t & 63, w = t >> 6;
    int r = blockIdx.x * 4 + w;
    const float* mp = minibuf + (size_t)r * NSAMP;
    unsigned key[12];
    #pragma unroll
    for (int s = 0; s < 12; ++s) key[s] = orderable(mp[lane + s * 64]);
    unsigned lo = 0, hi = 0x10000u;
    for (int it = 0; it < 16; ++it) {
        unsigned mid = (lo + hi) >> 1;
        unsigned mkey = mid << 16;
        int c = 0;
        #pragma unroll
        for (int s = 0; s < 12; ++s) c += (key[s] >= mkey) ? 1 : 0;
        #pragma unroll
        for (int d = 1; d < 64; d <<= 1) c += __shfl_xor(c, d);
        if (c >= KNN) lo = mid; else hi = mid;
    }
    if (lane == 0) {
        tauF[r] = (lo > 0u) ? unorderable((lo - 1u) << 16) : -3.4e38f;
    }
}

// ---------------- Kernel 3: SYMMETRIC neg-dist + dual-direction filter ----------------
// Upper-triangle tiles only (2080/batch). Own direction: ballot -> coalesced panel-C
// region. Transposed (offdiag): hi-PAIR coordinated via ballot bits (l31, l31+32) --
// both lanes keep identical per-column counters -> collision-free slots, race-free
// counts. Counts: own plain (p >= B), transposed packed 4xu8 (p < B). Overflow->ovbuf.
__global__ __launch_bounds__(256, 3) void k_distf(const unsigned short* __restrict__ xs,
                                                  const float* __restrict__ xx,
                                                  const float* __restrict__ tauF,
                                                  unsigned* __restrict__ cnt2d,
                                                  unsigned long long* __restrict__ cand,
                                                  unsigned* __restrict__ ovcnt,
                                                  unsigned long long* __restrict__ ovbuf) {
    __shared__ __align__(16) unsigned short Bsl[128][104];
    __shared__ float sxr[128];
    __shared__ float sxc[128];
    __shared__ float stauR[128];
    __shared__ float stauC[128];
    __shared__ unsigned tcl[128][4];
    int t = threadIdx.x;
    int lane = t & 63, wid = t >> 6;
    int l31 = lane & 31, hi = lane >> 5;

    int bx = blockIdx.x;
    int batch = (bx >= NTILE) ? 1 : 0;
    int ti = bx - batch * NTILE;
    int R = 0;
    while (ti >= 64 - R) { ti -= 64 - R; ++R; }
    int C = R + ti;
    bool offdiag = (R != C);
    int rowL0 = R * 128;
    int m0 = C * 128;
    int rowG0 = batch * 8192 + rowL0;
    int colG0 = batch * 8192 + m0;
    const unsigned short* xsb = xs + (size_t)batch * NPTS * 192;
    int n0w = rowL0 + wid * 32;

    f16x8 af[6];
    const unsigned short* arow = xsb + (size_t)(n0w + l31) * 192 + hi * 8;
    #pragma unroll
    for (int ks = 0; ks < 6; ++ks) af[ks] = *(const f16x8*)(arow + ks * 16);   // A-hi

    if (t < 128) {
        sxr[t] = xx[rowG0 + t];
        stauR[t] = tauF[rowG0 + t];
        sxc[t] = xx[colG0 + t];
        stauC[t] = tauF[colG0 + t];
    }

    f32x16 acc[4];
    #pragma unroll
    for (int ct = 0; ct < 4; ++ct)
        #pragma unroll
        for (int e = 0; e < 16; ++e) acc[ct][e] = 0.f;

    int sc2 = t >> 1, sh2 = t & 1;
    auto stageB = [&](int part) {
        const unsigned short* sb = xsb + (size_t)(m0 + sc2) * 192 + part * 96 + sh2 * 48;
        unsigned short* db = &Bsl[sc2][sh2 * 48];
        #pragma unroll
        for (int j = 0; j < 6; ++j) *(u16x8*)(db + j * 8) = *(const u16x8*)(sb + j * 8);
    };
    auto mmpass = [&]() {
        #pragma unroll
        for (int ks = 0; ks < 6; ++ks)
            #pragma unroll
            for (int ct = 0; ct < 4; ++ct) {
                f16x8 bf = *(const f16x8*)&Bsl[ct * 32 + l31][ks * 16 + hi * 8];
                acc[ct] = __builtin_amdgcn_mfma_f32_32x32x16_f16(af[ks], bf, acc[ct], 0, 0, 0);
            }
    };

    stageB(1);                   // B lo
    __syncthreads();
    mmpass();                    // hA*lB
    __syncthreads();
    stageB(0);                   // B hi
    __syncthreads();
    mmpass();                    // hA*hB
    #pragma unroll
    for (int ks = 0; ks < 6; ++ks) af[ks] = *(const f16x8*)(arow + 96 + ks * 16);  // A-lo
    mmpass();                    // lA*hB

    float xc[4], stC[4];
    #pragma unroll
    for (int ct = 0; ct < 4; ++ct) {
        xc[ct] = sxc[ct * 32 + l31];
        stC[ct] = stauC[ct * 32 + l31];
    }
    unsigned tq[4] = {0u, 0u, 0u, 0u};       // per-column counts, SYNCED across hi pair
    #pragma unroll
    for (int q = 0; q < 4; ++q)
        #pragma unroll
        for (int rr = 0; rr < 4; ++rr) {
            int rowin = wid * 32 + 4 * hi + 8 * q + rr;
            int grow = rowG0 + rowin;
            float xr = sxr[rowin];
            float tau = stauR[rowin];
            unsigned cnt_run = 0;
            size_t base = (size_t)grow * ROWSLOT + (size_t)C * PSLOT;
            #pragma unroll
            for (int ct = 0; ct < 4; ++ct) {
                float valx = 2.f * acc[ct][q * 4 + rr] - xr - xc[ct];
                // own direction (row grow, col in panel C)
                bool p = (valx >= tau);
                unsigned long long bal = __ballot(p);
                unsigned hm = hi ? (unsigned)(bal >> 32) : (unsigned)bal;
                if (p) {
                    unsigned key = orderable(valx);
                    unsigned pos = cnt_run + (unsigned)__popc(hm & ((1u << l31) - 1u));
                    unsigned long long e = ((unsigned long long)key << 32)
                                         | (unsigned)(m0 + ct * 32 + l31);
                    if (pos < PSLOT) {
                        cand[base + pos] = e;
                    } else {
                        unsigned o = atomicAdd(&ovcnt[grow], 1u);
                        if (o < OVCAP) ovbuf[(size_t)grow * OVCAP + o] = e;
                    }
                }
                cnt_run += (unsigned)__popc(hm);
                // transposed direction (row = this col, col = this row's point)
                if (offdiag) {
                    bool pt = (valx >= stC[ct]);
                    unsigned long long balT = __ballot(pt);
                    unsigned b0 = (unsigned)((balT >> l31) & 1ull);
                    unsigned b1 = (unsigned)((balT >> (l31 + 32)) & 1ull);
                    if (pt) {
                        unsigned pos = tq[ct] + (hi ? b0 : 0u);
                        int cG = colG0 + ct * 32 + l31;
                        unsigned keyt = orderable(valx);
                        unsigned long long et = ((unsigned long long)keyt << 32)
                                              | (unsigned)(rowL0 + rowin);
                        if (pos < TSLOT) {
                            cand[(size_t)cG * ROWSLOT + (size_t)R * PSLOT
                                 + (size_t)wid * TSLOT + pos] = et;
                        } else {
                            unsigned o = atomicAdd(&ovcnt[cG], 1u);
                            if (o < OVCAP) ovbuf[(size_t)cG * OVCAP + o] = et;
                        }
                    }
                    tq[ct] += b0 + b1;       // both hi lanes stay in lockstep
                }
            }
            if (l31 == 0)
                cnt2d[(size_t)grow * NPAN + C] = (cnt_run < PSLOT) ? cnt_run : PSLOT;
        }
    if (offdiag) {
        #pragma unroll
        for (int ct = 0; ct < 4; ++ct) {
            unsigned tv = tq[ct];
            tcl[ct * 32 + l31][wid] = (tv < (unsigned)TSLOT) ? tv : (unsigned)TSLOT;
        }
        __syncthreads();
        if (t < 128) {
            unsigned pq = tcl[t][0] | (tcl[t][1] << 8) | (tcl[t][2] << 16) | (tcl[t][3] << 24);
            cnt2d[(size_t)(colG0 + t) * NPAN + R] = pq;
        }
    }
}

// ---------------- Kernel 4: merge candidates + spills -> exact top-20 ----------------
__global__ __launch_bounds__(256) void k_mrg(const unsigned long long* __restrict__ cand,
                                             const unsigned* __restrict__ cnt2d,
                                             const unsigned* __restrict__ ovcnt,
                                             const unsigned long long* __restrict__ ovbuf,
                                             int* __restrict__ idxOut) {
    int t = threadIdx.x;
    int lane = t & 63, w = t >> 6;
    int r = blockIdx.x * 4 + w;
    int B = (r & 8191) >> 7;                 // row block within batch
    __shared__ unsigned scc[4][NPAN];
    scc[w][lane] = cnt2d[(size_t)r * NPAN + lane];
    WAVESYNC();
    const unsigned long long* cp = cand + (size_t)r * ROWSLOT;
    unsigned long long pk[CAPS + 1];
    #pragma unroll
    for (int s = 0; s < CAPS; ++s) {
        int slot = lane + 64 * s;
        int panel = slot / PSLOT;
        int within = slot - panel * PSLOT;
        unsigned cc = scc[w][panel];
        bool valid;
        if (panel >= B) {
            valid = within < (int)cc;                    // own count (<= 12)
        } else {
            int wv = within / TSLOT;
            int ws = within - wv * TSLOT;
            valid = ws < (int)((cc >> (8 * wv)) & 255u); // packed 4xu8 wave counts
        }
        pk[s] = valid ? cp[slot] : 0ull;     // key 0 << real keys
    }
    int ovn = (int)ovcnt[r]; if (ovn > OVCAP) ovn = OVCAP;
    pk[CAPS] = (lane < ovn) ? ovbuf[(size_t)r * OVCAP + lane] : 0ull;

    unsigned lo = 0, hi = 0x10000u;
    for (int it = 0; it < 16; ++it) {
        unsigned mid = (lo + hi) >> 1;
        unsigned mkey = mid << 16;
        int c = 0;
        #pragma unroll
        for (int s = 0; s <= CAPS; ++s) c += ((unsigned)(pk[s] >> 32) >= mkey) ? 1 : 0;
        #pragma unroll
        for (int d = 1; d < 64; d <<= 1) c += __shfl_xor(c, d);
        if (c >= KNN) lo = mid; else hi = mid;
    }
    unsigned thr = lo << 16;

    __shared__ unsigned long long sk[4][128];
    __shared__ int sn[4];
    if (lane == 0) sn[w] = 0;
    WAVESYNC();
    #pragma unroll
    for (int s = 0; s <= CAPS; ++s) {
        if ((unsigned)(pk[s] >> 32) >= thr) {
            int j = atomicAdd(&sn[w], 1);
            if (j < 128) sk[w][j] = pk[s];
        }
    }
    WAVESYNC();
    int nc = sn[w]; if (nc > 128) nc = 128;
    #pragma unroll
    for (int half = 0; half < 2; ++half) {
        int i = lane + half * 64;
        if (i < nc) {
            unsigned long long me = sk[w][i];
            unsigned km = (unsigned)(me >> 32), cm = (unsigned)me;
            int rank = 0;
            for (int j = 0; j < nc; ++j) {
                unsigned long long o = sk[w][j];
                unsigned ko = (unsigned)(o >> 32), co = (unsigned)o;
                rank += (ko > km || (ko == km && co < cm)) ? 1 : 0;
            }
            if (rank < KNN) idxOut[(size_t)r * KNN + rank] = (int)cm;
        }
    }
}

// ---------------- Kernel 5: u = A*x_point, v = (B-A)*x_point ----------------
__global__ __launch_bounds__(256) void k_uv(const float* __restrict__ x,
                                            const float* __restrict__ W1,
                                            float* __restrict__ u,
                                            float* __restrict__ v) {
    __shared__ float sA[64 * 33];
    __shared__ float sV[64 * 33];
    __shared__ float sxf[FDIM * 16];
    int t = threadIdx.x;
    for (int i = t; i < 64 * 32; i += 256) {
        int o = i >> 5, c = i & 31;
        float a = W1[o * 64 + c];
        sA[o * 33 + c] = a;
        sV[o * 33 + c] = W1[o * 64 + 32 + c] - a;
    }
    int p0 = blockIdx.x * 16;
    int b = p0 >> 13, nb = p0 & 8191;
    const float* xf = x + (size_t)b * FDIM * NPTS;
    for (int i = t; i < FDIM * 16; i += 256) {
        int f = i >> 4, p = i & 15;
        sxf[f * 16 + p] = xf[(size_t)f * NPTS + nb + p];
    }
    __syncthreads();
    #pragma unroll
    for (int ii = 0; ii < 4; ++ii) {
        int it = t + 256 * ii;
        int o = it & 63, p = it >> 6;
        float u0 = 0.f, u1 = 0.f, u2 = 0.f, w0 = 0.f, w1 = 0.f, w2 = 0.f;
        #pragma unroll
        for (int c = 0; c < 32; ++c) {
            float a = sA[o * 33 + c];
            float wv = sV[o * 33 + c];
            float x0 = sxf[(c * 3 + 0) * 16 + p];
            float x1 = sxf[(c * 3 + 1) * 16 + p];
            float x2 = sxf[(c * 3 + 2) * 16 + p];
            u0 += a * x0;  u1 += a * x1;  u2 += a * x2;
            w0 += wv * x0; w1 += wv * x1; w2 += wv * x2;
        }
        size_t base = ((size_t)(p0 + p) * 64 + o) * 3;
        u[base] = u0; u[base + 1] = u1; u[base + 2] = u2;
        v[base] = w0; v[base + 1] = w1; v[base + 2] = w2;
    }
}

// ---------------- Kernel 6: BN stats partials ----------------
__global__ __launch_bounds__(256) void k_stats(const float* __restrict__ u,
                                               const float* __restrict__ v,
                                               const int* __restrict__ idx,
                                               float* __restrict__ partial) {
    int blk = blockIdx.x, t = threadIdx.x;
    int o = t & 63, sub = t >> 6;
    int p0 = blk * 8;
    __shared__ float svf[8 * 192];
    __shared__ int sjf[8 * KNN];
    for (int i = t; i < 8 * 192; i += 256) svf[i] = v[(size_t)p0 * 192 + i];
    for (int i = t; i < 8 * KNN; i += 256) sjf[i] = idx[(size_t)p0 * KNN + i];
    __syncthreads();
    float s1 = 0.f, s2 = 0.f;
    for (int p = 0; p < 8; ++p) {
        int gpt = p0 + p;
        size_t ubase = (size_t)(gpt >> 13) * NPTS * 192;
        const float* vp = &svf[p * 192 + o * 3];
        float v0 = vp[0], v1 = vp[1], v2 = vp[2];
        for (int kk = sub; kk < KNN; kk += 4) {
            int j = sjf[p * KNN + kk];
            const float* up = u + ubase + (size_t)j * 192 + o * 3;
            float q0 = up[0] + v0, q1 = up[1] + v1, q2 = up[2] + v2;
            float nrm = sqrtf(q0 * q0 + q1 * q1 + q2 * q2) + VN_EPS;
            s1 += nrm;
            s2 += nrm * nrm;
        }
    }
    __shared__ float r1[256], r2[256];
    r1[t] = s1; r2[t] = s2;
    __syncthreads();
    if (t < 64) {
        float a1 = r1[t] + r1[t + 64] + r1[t + 128] + r1[t + 192];
        float a2 = r2[t] + r2[t + 64] + r2[t + 128] + r2[t + 192];
        partial[(size_t)blk * 128 + t] = a1;
        partial[(size_t)blk * 128 + 64 + t] = a2;
    }
}

// ---------------- Kernel 7: reduce stats -> gs, bs ----------------
__global__ __launch_bounds__(256) void k_reduce(const float* __restrict__ partial,
                                                const float* __restrict__ gamma,
                                                const float* __restrict__ beta,
                                                float* __restrict__ gsbs) {
    int ch = blockIdx.x, t = threadIdx.x;
    float s1 = 0.f, s2 = 0.f;
    for (int i = t; i < 2048; i += 256) {
        s1 += partial[(size_t)i * 128 + ch];
        s2 += partial[(size_t)i * 128 + 64 + ch];
    }
    __shared__ float r1[256], r2[256];
    r1[t] = s1; r2[t] = s2;
    __syncthreads();
    for (int s = 128; s > 0; s >>= 1) {
        if (t < s) { r1[t] += r1[t + s]; r2[t] += r2[t + s]; }
        __syncthreads();
    }
    if (t == 0) {
        const float cnt2 = (float)(NB * NPTS * KNN);
        float mean = r1[0] / cnt2;
        float var = r2[0] / cnt2 - mean * mean;
        float inv = 1.0f / sqrtf(var + VN_BN_EPS);
        float g = gamma[ch] * inv;
        gsbs[ch] = g;
        gsbs[64 + ch] = beta[ch] - mean * g;
    }
}

// ---------------- Kernel 8: fused BN + VN-LeakyReLU + mean, ONE WAVE per point ----------------
__global__ __launch_bounds__(64) void k_final(const float* __restrict__ u,
                                              const float* __restrict__ v,
                                              const int* __restrict__ idx,
                                              const float* __restrict__ Wd,
                                              const float* __restrict__ gsbs,
                                              float* __restrict__ out) {
    int lane = threadIdx.x;
    int l31 = lane & 31, hi = lane >> 5;
    int gpt = blockIdx.x;                         // global point b*N+n
    int b = gpt >> 13, n = gpt & 8191;

    __shared__ __align__(16) unsigned short Qw[30 * 72];  // f16
    __shared__ __align__(16) float Dw[30 * 64];           // f32

    f16x8 Bf[2][4];
    #pragma unroll
    for (int ct = 0; ct < 2; ++ct)
        #pragma unroll
        for (int ks = 0; ks < 4; ++ks) {
            const float* wp = Wd + (size_t)(ct * 32 + l31) * 64 + ks * 16 + hi * 8;
            f16x8 f;
            #pragma unroll
            for (int jj = 0; jj < 8; ++jj) f[jj] = (_Float16)wp[jj];
            Bf[ct][ks] = f;
        }

    float gso = gsbs[lane], bso = gsbs[64 + lane];
    size_t vb = (size_t)gpt * 192 + lane * 3;
    float v0 = v[vb], v1 = v[vb + 1], v2 = v[vb + 2];
    const int* jrow = idx + (size_t)gpt * KNN;
    size_t ubase = (size_t)b * NPTS * 192;
    float a0 = 0.f, a1 = 0.f, a2 = 0.f;

    for (int h = 0; h < 2; ++h) {
        #pragma unroll
        for (int kl = 0; kl < 10; ++kl) {
            int j = jrow[h * 10 + kl];
            const float* up = u + ubase + (size_t)j * 192 + lane * 3;
            float q0 = up[0] + v0, q1 = up[1] + v1, q2 = up[2] + v2;
            float nrm = sqrtf(q0 * q0 + q1 * q1 + q2 * q2) + VN_EPS;
            float f = (gso * nrm + bso) / nrm;
            q0 *= f; q1 *= f; q2 *= f;
            union { _Float16 f16; unsigned short u16; } c0, c1, c2;
            c0.f16 = (_Float16)q0; c1.f16 = (_Float16)q1; c2.f16 = (_Float16)q2;
            Qw[(3 * kl + 0) * 72 + lane] = c0.u16;
            Qw[(3 * kl + 1) * 72 + lane] = c1.u16;
            Qw[(3 * kl + 2) * 72 + lane] = c2.u16;
        }
        WAVESYNC();
        f32x16 acc[2];
        #pragma unroll
        for (int ct = 0; ct < 2; ++ct)
            #pragma unroll
            for (int e = 0; e < 16; ++e) acc[ct][e] = 0.f;
        #pragma unroll
        for (int ks = 0; ks < 4; ++ks) {
            f16x8 af = *(const f16x8*)&Qw[l31 * 72 + ks * 16 + hi * 8];
            acc[0] = __builtin_amdgcn_mfma_f32_32x32x16_f16(af, Bf[0][ks], acc[0], 0, 0, 0);
            acc[1] = __builtin_amdgcn_mfma_f32_32x32x16_f16(af, Bf[1][ks], acc[1], 0, 0, 0);
        }
        #pragma unroll
        for (int ct = 0; ct < 2; ++ct)
            #pragma unroll
            for (int q = 0; q < 4; ++q)
                #pragma unroll
                for (int r = 0; r < 4; ++r) {
                    int row = 4 * hi + 8 * q + r;
                    if (row < 30) Dw[row * 64 + ct * 32 + l31] = acc[ct][q * 4 + r];
                }
        WAVESYNC();
        #pragma unroll
        for (int kl = 0; kl < 10; ++kl) {
            float qd[3], dd[3];
            #pragma unroll
            for (int d = 0; d < 3; ++d) {
                union { unsigned short u16; _Float16 f16; } rr;
                rr.u16 = Qw[(3 * kl + d) * 72 + lane];
                qd[d] = (float)rr.f16;
                dd[d] = Dw[(3 * kl + d) * 64 + lane];
            }
            float dot = qd[0] * dd[0] + qd[1] * dd[1] + qd[2] * dd[2];
            float dn = dd[0] * dd[0] + dd[1] * dd[1] + dd[2] * dd[2];
            float coef = (dot >= 0.f) ? 0.f : 0.8f * dot / (dn + VN_EPS);
            a0 += qd[0] - coef * dd[0];
            a1 += qd[1] - coef * dd[1];
            a2 += qd[2] - coef * dd[2];
        }
        WAVESYNC();
    }
    float s = 1.f / (float)KNN;
    size_t ob = ((size_t)(b * 64 + lane) * 3) * NPTS + n;
    out[ob] = a0 * s;
    out[ob + NPTS] = a1 * s;
    out[ob + 2 * NPTS] = a2 * s;
}

// ---------------- host ----------------
extern "C" void kernel_launch(void* const* d_in, const int* in_sizes, int n_in,
                              void* d_out, int out_size, void* d_ws, size_t ws_size,
                              hipStream_t stream) {
    const float* x = (const float*)d_in[0];
    const float* W1 = (const float*)d_in[1];
    const float* Wd = (const float*)d_in[2];
    const float* gamma = (const float*)d_in[3];
    const float* beta = (const float*)d_in[4];
    float* out = (float*)d_out;

    char* ws = (char*)d_ws;
    size_t off = 0;
    auto alloc = [&](size_t bytes) {
        void* p = ws + off;
        off = (off + bytes + 255) & ~(size_t)255;
        return p;
    };
    const int totalRows = NB * NPTS;                 // 16384
    float* xxp = (float*)alloc((size_t)totalRows * 4);
    int* idxp = (int*)alloc((size_t)totalRows * KNN * 4);
    float* up = (float*)alloc((size_t)totalRows * 192 * 4);
    float* vp = (float*)alloc((size_t)totalRows * 192 * 4);
    float* partial = (float*)alloc((size_t)2048 * 128 * 4);
    float* gsbs = (float*)alloc(512);
    unsigned short* xsp = (unsigned short*)alloc((size_t)totalRows * 192 * 2);
    float* tauFp = (float*)alloc((size_t)totalRows * 4);
    unsigned* cnt2d = (unsigned*)alloc((size_t)totalRows * NPAN * 4);      // 4 MB
    unsigned* ovcnt = (unsigned*)alloc((size_t)totalRows * 4);             // 64 KB
    unsigned long long* ovbuf = (unsigned long long*)alloc((size_t)totalRows * OVCAP * 8); // 8 MB
    // union region: minibuf (50 MB) dead after k_thrsel; cand (101 MB) after
    void* region = alloc((size_t)totalRows * ROWSLOT * 8);
    float* minibuf = (float*)region;
    unsigned long long* cand = (unsigned long long*)region;

    hipMemsetAsync(ovcnt, 0, (size_t)totalRows * 4, stream);

    k_prep<<<totalRows / 256, 256, 0, stream>>>(x, xxp, xsp);

    k_thr<<<dim3(totalRows / 128, NSAMP / 128), 256, 0, stream>>>(xsp, xxp, minibuf);
    k_thrsel<<<totalRows / 4, 256, 0, stream>>>(minibuf, tauFp);
    k_distf<<<NB * NTILE, 256, 0, stream>>>(xsp, xxp, tauFp, cnt2d, cand, ovcnt, ovbuf);
    k_mrg<<<totalRows / 4, 256, 0, stream>>>(cand, cnt2d, ovcnt, ovbuf, idxp);

    k_uv<<<totalRows / 16, 256, 0, stream>>>(x, W1, up, vp);
    k_stats<<<totalRows / 8, 256, 0, stream>>>(up, vp, idxp, partial);
    k_reduce<<<64, 256, 0, stream>>>(partial, gamma, beta, gsbs);
    k_final<<<totalRows, 64, 0, stream>>>(up, vp, idxp, Wd, gsbs, out);
}